// Round 1
// baseline (236.348 us; speedup 1.0000x reference)
//
#include <hip/hip_runtime.h>

#define S_LEN 2048
#define DH 64

typedef float f32x4 __attribute__((ext_vector_type(4)));
typedef __bf16 bf16x8 __attribute__((ext_vector_type(8)));

#define PTS 72   // P row stride (bf16 elems) for 64 keys + pad
#define MFMA16(A, B, C) __builtin_amdgcn_mfma_f32_16x16x32_bf16(A, B, C, 0, 0, 0)

__device__ __forceinline__ unsigned short f2bf(float f) {
    unsigned u = __builtin_bit_cast(unsigned, f);
    u += 0x7fffu + ((u >> 16) & 1u);
    return (unsigned short)(u >> 16);
}

__device__ __forceinline__ uint4 pack8(const float* s) {
    unsigned short h[8];
#pragma unroll
    for (int i = 0; i < 8; ++i) h[i] = f2bf(s[i]);
    return *(const uint4*)h;
}

// truncating pack (1 VALU op); bias cancels in O = (P V)/(P 1)
__device__ __forceinline__ unsigned pack_tr(float a, float b) {
    return __builtin_amdgcn_perm(__builtin_bit_cast(unsigned, b),
                                 __builtin_bit_cast(unsigned, a), 0x07060302u);
}

__device__ __forceinline__ bf16x8 ld128(const unsigned short* p) {
    return __builtin_bit_cast(bf16x8, *(const uint4*)p);
}

__device__ __forceinline__ bf16x8 ones8() {
    uint4 ou; ou.x = 0x3F803F80u; ou.y = ou.x; ou.z = ou.x; ou.w = ou.x;
    return __builtin_bit_cast(bf16x8, ou);
}

// ---------------- fused pre-pass: K and V -> swizzled bf16 tile images -----
__global__ __launch_bounds__(256) void prep_kv(const float* __restrict__ k,
                                               const float* __restrict__ v,
                                               uint4* __restrict__ kimg,
                                               uint4* __restrict__ vimg) {
    __shared__ unsigned short tr[64 * 40];
    const int bid = blockIdx.x;
    const int t = threadIdx.x;
    if (bid < 4096) {
        const int r = t >> 3, b = t & 7;
        const int srcblk = b ^ (r & 7);
        const float* src = k + ((size_t)bid * 32 + r) * 64 + srcblk * 8;
        float buf[8];
        *(float4*)&buf[0] = *(const float4*)src;
        *(float4*)&buf[4] = *(const float4*)(src + 4);
        kimg[(size_t)bid * 256 + t] = pack8(buf);
    } else {
        const int vb = bid - 4096;
        const int r = t >> 3, cb = t & 7;
        const float* src = v + ((size_t)vb * 32 + r) * 64 + cb * 8;
        float buf[8];
        *(float4*)&buf[0] = *(const float4*)src;
        *(float4*)&buf[4] = *(const float4*)(src + 4);
#pragma unroll
        for (int i = 0; i < 8; ++i)
            tr[(cb * 8 + i) * 40 + r] = f2bf(buf[i]);
        __syncthreads();
        const int d = t >> 2, kb = t & 3;
        const int skb = kb ^ ((d >> 1) & 3);
        vimg[(size_t)vb * 256 + t] = *(const uint4*)&tr[d * 40 + skb * 8];
    }
}

// ---------------- main kernel helpers -------------------------------------
// SM: 1 = fully unmasked subtile, 2 = diagonal subtile (position == wave).
// At the diagonal, the triangular mask is purely local: key (quad*4+r) vs
// row c within the mt == wave 16x16 block; mt > wave is fully masked ->
// store zero P (it may be read by the PV half covering those keys).
template <int SM>
__device__ __forceinline__ void sub_mt(
    const bf16x8 ka0, const bf16x8 ka1, const bf16x8 q0, const bf16x8 q1,
    unsigned short* __restrict__ pw, int mt, int wave, int quad, int c)
{
    unsigned* pb = (unsigned*)pw + c * (PTS / 2) + mt * 8 + quad * 2;
    if (SM == 2 && mt > wave) {
        *(uint2*)pb = make_uint2(0u, 0u);
        return;
    }
    f32x4 s = (f32x4){0.f, 0.f, 0.f, 0.f};
    s = MFMA16(ka0, q0, s);
    s = MFMA16(ka1, q1, s);
    float p[4];
#pragma unroll
    for (int r = 0; r < 4; ++r) {
        float e = __builtin_amdgcn_exp2f(s[r]);
        if (SM == 2 && mt == wave) e = (quad * 4 + r > c) ? 0.f : e;
        p[r] = e;
    }
    *(uint2*)pb = make_uint2(pack_tr(p[0], p[1]), pack_tr(p[2], p[3]));
}

// AM: mode of subtile A (0 skip, 1 full, 2 diag); BM: mode of subtile B (1/2).
// Never both diag (A's diag jt == pi < 16 <= 31 - pi == B's diag jt).
template <int AM, int BM>
__device__ __forceinline__ void body64(
    const unsigned short* __restrict__ kt, const unsigned short* __restrict__ vt,
    unsigned short* __restrict__ pw0, unsigned short* __restrict__ pw1,
    const bf16x8* qf, f32x4 acc[2][4], f32x4* accl,
    int wave, int quad, int c)
{
    const int sw = c & 7;
    const bf16x8 ones = ones8();

#pragma unroll
    for (int mt = 0; mt < 4; ++mt) {
        bf16x8 ka0 = ones, ka1 = ones;
        const bool need_k = (AM == 1 || BM == 1) || (mt <= wave);
        if (need_k) {
            const unsigned short* kr = kt + (mt * 16 + c) * 64;
            ka0 = ld128(kr + ((quad ^ sw) << 3));
            ka1 = ld128(kr + (((quad | 4) ^ sw) << 3));
        }
        if constexpr (AM != 0) sub_mt<AM>(ka0, ka1, qf[0], qf[1], pw0, mt, wave, quad, c);
        if constexpr (BM != 0) sub_mt<BM>(ka0, ka1, qf[2], qf[3], pw1, mt, wave, quad, c);
    }

    // second 32-key half is live unless we're a diag subtile with wave < 2
    const bool hA = (AM == 1) || (wave >= 2);
    const bool hB = (BM == 1) || (wave >= 2);

    // ---- P fragments (A-layout) + l via ones-MFMA ----
    bf16x8 pfA0 = ones, pfA1 = ones, pfB0 = ones, pfB1 = ones;
    if constexpr (AM != 0) {
        pfA0 = ld128(pw0 + c * PTS + quad * 8);
        accl[0] = MFMA16(pfA0, ones, accl[0]);
        if (hA) {
            pfA1 = ld128(pw0 + c * PTS + 32 + quad * 8);
            accl[0] = MFMA16(pfA1, ones, accl[0]);
        }
    }
    if constexpr (BM != 0) {
        pfB0 = ld128(pw1 + c * PTS + quad * 8);
        accl[1] = MFMA16(pfB0, ones, accl[1]);
        if (hB) {
            pfB1 = ld128(pw1 + c * PTS + 32 + quad * 8);
            accl[1] = MFMA16(pfB1, ones, accl[1]);
        }
    }

    // ---- O += P . V (V-frags shared across active subtiles) ----
    const int vsw = (c >> 1) & 3;
#pragma unroll
    for (int dc = 0; dc < 4; ++dc) {
        const unsigned short* vr = vt + (dc * 16 + c) * 32 + ((quad ^ vsw) << 3);
        const bf16x8 vf0 = ld128(vr);
        if constexpr (AM != 0) acc[0][dc] = MFMA16(pfA0, vf0, acc[0][dc]);
        if constexpr (BM != 0) acc[1][dc] = MFMA16(pfB0, vf0, acc[1][dc]);
        const bool need2 = (AM != 0 && hA) || (BM != 0 && hB);
        if (need2) {
            const bf16x8 vf1 = ld128(vr + 2048);
            if constexpr (AM != 0) { if (hA) acc[0][dc] = MFMA16(pfA1, vf1, acc[0][dc]); }
            if constexpr (BM != 0) { if (hB) acc[1][dc] = MFMA16(pfB1, vf1, acc[1][dc]); }
        }
    }
}

// ---------------- main kernel: mirrored-pair schedule ----------------------
// Block pi (0..15) owns 64-row chunk pi (top half) + chunk 31-pi (bottom
// half). Each wave owns 16-row tile 4*pi+wave (subtile A, diag at jt==pi)
// and its causal mirror 4*(31-pi)+wave (subtile B, diag at jt==31-pi).
// Every wave executes exactly ~33 16x64 subtile-bodies -> uniform runtime
// across all waves/blocks/CUs regardless of dispatch order. Both tiles sit
// at position `wave` within their diagonal 64-key tile.
__global__ __launch_bounds__(256, 4) void fa_kernel(
    const float* __restrict__ q,
    const uint4* __restrict__ kimg,
    const uint4* __restrict__ vimg,
    float* __restrict__ out)
{
    __shared__ unsigned short kt[64 * 64];        // 8 KB
    __shared__ unsigned short vt[2 * 64 * 32];    // 8 KB
    __shared__ unsigned short pt[4][2][16 * PTS]; // 18 KB

    const int tid  = threadIdx.x;
    const int lane = tid & 63;
    const int wave = tid >> 6;
    const int quad = lane >> 4;
    const int c    = lane & 15;

    const int bid = blockIdx.x;
    const int bh  = bid & 63;
    const int pi  = bid >> 6;                     // 0..15

    const int qa = (pi * 4 + wave) * 16;          // subtile A base row
    const int qb = ((31 - pi) * 4 + wave) * 16;   // subtile B base row
    const int jt_last = 31 - pi;

    const size_t head_off = (size_t)bh * S_LEN * DH;

    // Q fragments for both 16-row tiles, pre-scaled into log2 domain
    const float SCALE = 0.125f * 1.4426950408889634f;
    bf16x8 qf[4];
#pragma unroll
    for (int s = 0; s < 2; ++s) {
        const int base = s ? qb : qa;
        const float* qrow = q + head_off + (size_t)(base + c) * DH;
        float t0[8], t1[8];
#pragma unroll
        for (int i = 0; i < 8; ++i) t0[i] = qrow[quad * 8 + i] * SCALE;
#pragma unroll
        for (int i = 0; i < 8; ++i) t1[i] = qrow[32 + quad * 8 + i] * SCALE;
        qf[s * 2 + 0] = __builtin_bit_cast(bf16x8, pack8(t0));
        qf[s * 2 + 1] = __builtin_bit_cast(bf16x8, pack8(t1));
    }

    f32x4 acc[2][4];
#pragma unroll
    for (int s = 0; s < 2; ++s)
#pragma unroll
        for (int dc = 0; dc < 4; ++dc) acc[s][dc] = (f32x4){0.f, 0.f, 0.f, 0.f};
    f32x4 accl[2];
    accl[0] = (f32x4){0.f, 0.f, 0.f, 0.f};
    accl[1] = (f32x4){0.f, 0.f, 0.f, 0.f};

    const uint4* kin = kimg + (size_t)bh * 64 * 256 + tid;
    const uint4* vin = vimg + (size_t)bh * 64 * 256 + tid;
    unsigned short* pw0 = pt[wave][0];
    unsigned short* pw1 = pt[wave][1];

    uint4 kA = kin[0], kB = kin[256];
    uint4 vA = vin[0], vB = vin[256];
    for (int jt = 0; jt <= jt_last; ++jt) {
        __syncthreads();
        ((uint4*)kt)[tid] = kA;  ((uint4*)kt)[tid + 256] = kB;
        ((uint4*)vt)[tid] = vA;  ((uint4*)vt)[tid + 256] = vB;
        if (jt < jt_last) {
            kA = kin[(jt + 1) * 512];  kB = kin[(jt + 1) * 512 + 256];
            vA = vin[(jt + 1) * 512];  vB = vin[(jt + 1) * 512 + 256];
        }
        __syncthreads();

        if (jt < pi)
            body64<1, 1>(kt, vt, pw0, pw1, qf, acc, accl, wave, quad, c);
        else if (jt == pi)
            body64<2, 1>(kt, vt, pw0, pw1, qf, acc, accl, wave, quad, c);
        else if (jt < jt_last)
            body64<0, 1>(kt, vt, pw0, pw1, qf, acc, accl, wave, quad, c);
        else
            body64<0, 2>(kt, vt, pw0, pw1, qf, acc, accl, wave, quad, c);
    }

    // ---- epilogue: l lives in accl (row = quad*4+r), normalize, store ----
    float* ob = out + head_off;
#pragma unroll
    for (int s = 0; s < 2; ++s) {
        const int base = s ? qb : qa;
        float linv[4];
#pragma unroll
        for (int r = 0; r < 4; ++r) linv[r] = 1.0f / accl[s][r];
#pragma unroll
        for (int dc = 0; dc < 4; ++dc)
#pragma unroll
            for (int r = 0; r < 4; ++r) {
                const size_t idx =
                    (size_t)(base + quad * 4 + r) * DH + dc * 16 + c;
                ob[idx] = acc[s][dc][r] * linv[r];
            }
    }
}

// ---------------- fallback (round-2 style, used if ws too small) ----------
#define KT_STRIDE 88
#define VT_STRIDE 36
__global__ __launch_bounds__(256) void fa_kernel_fb(
    const float* __restrict__ q, const float* __restrict__ k,
    const float* __restrict__ v, float* __restrict__ out)
{
    __shared__ unsigned short kts[32 * KT_STRIDE];
    __shared__ unsigned short vts[64 * VT_STRIDE];
    __shared__ unsigned short pts[4][16 * 40];
    const int tid = threadIdx.x, lane = tid & 63, wave = tid >> 6;
    const int quad = lane >> 4, c = lane & 15;
    const int bid = blockIdx.x, bh = bid & 63, qblk = 31 - (bid >> 6);
    const int qtile = qblk * 4 + wave, qbase = qtile * 16;
    const int my_diag = qtile >> 1, jt_last = (qblk * 4 + 3) >> 1;
    const size_t head_off = (size_t)bh * S_LEN * DH;
    const float* qrow = q + head_off + (size_t)(qbase + c) * DH;
    float qtmp[8];
#pragma unroll
    for (int i = 0; i < 8; ++i) qtmp[i] = qrow[quad * 8 + i];
    bf16x8 qf0 = __builtin_bit_cast(bf16x8, pack8(qtmp));
#pragma unroll
    for (int i = 0; i < 8; ++i) qtmp[i] = qrow[32 + quad * 8 + i];
    bf16x8 qf1 = __builtin_bit_cast(bf16x8, pack8(qtmp));
    f32x4 acc[4];
#pragma unroll
    for (int dc = 0; dc < 4; ++dc) acc[dc] = (f32x4){0.f, 0.f, 0.f, 0.f};
    float m_run = -1e30f, l_run = 0.f;
    const int ig = qbase + c;
    const int srow = tid >> 3, sdb = tid & 7;
    const int vcol = (((srow >> 3) ^ (sdb & 3)) << 3) | (srow & 7);
    const float LOG2E = 1.4426950408889634f;
    for (int jt = 0; jt <= jt_last; ++jt) {
        __syncthreads();
        {
            const size_t g = head_off + (size_t)(jt * 32 + srow) * DH + sdb * 8;
            float kbuf[8];
            *(float4*)&kbuf[0] = *(const float4*)(k + g);
            *(float4*)&kbuf[4] = *(const float4*)(k + g + 4);
            *(uint4*)&kts[srow * KT_STRIDE + sdb * 8] = pack8(kbuf);
            float vbuf[8];
            *(float4*)&vbuf[0] = *(const float4*)(v + g);
            *(float4*)&vbuf[4] = *(const float4*)(v + g + 4);
#pragma unroll
            for (int i = 0; i < 8; ++i)
                vts[(sdb * 8 + i) * VT_STRIDE + vcol] = f2bf(vbuf[i]);
        }
        __syncthreads();
        if (jt > my_diag) continue;
        f32x4 st[2];
#pragma unroll
        for (int mt = 0; mt < 2; ++mt) {
            const unsigned short* krow = &kts[(mt * 16 + c) * KT_STRIDE + quad * 8];
            bf16x8 ka0 = __builtin_bit_cast(bf16x8, *(const uint4*)krow);
            bf16x8 ka1 = __builtin_bit_cast(bf16x8, *(const uint4*)(krow + 32));
            f32x4 a = (f32x4){0.f, 0.f, 0.f, 0.f};
            a = MFMA16(ka0, qf0, a);
            a = MFMA16(ka1, qf1, a);
            st[mt] = a;
        }
        float tv[8];
#pragma unroll
        for (int mt = 0; mt < 2; ++mt)
#pragma unroll
            for (int r = 0; r < 4; ++r) {
                const int jg = jt * 32 + mt * 16 + quad * 4 + r;
                const float s = st[mt][r] * 0.125f;
                tv[mt * 4 + r] = (jg > ig) ? -1e30f : s;
            }
        float tm = tv[0];
#pragma unroll
        for (int i = 1; i < 8; ++i) tm = fmaxf(tm, tv[i]);
        tm = fmaxf(tm, __shfl_xor(tm, 16, 64));
        tm = fmaxf(tm, __shfl_xor(tm, 32, 64));
        const float m_new = fmaxf(m_run, tm);
        const float mb = m_new * LOG2E;
        float p[8], ps = 0.f;
#pragma unroll
        for (int i = 0; i < 8; ++i) {
            p[i] = __builtin_amdgcn_exp2f(tv[i] * LOG2E - mb);
            ps += p[i];
        }
        ps += __shfl_xor(ps, 16, 64);
        ps += __shfl_xor(ps, 32, 64);
        const float alpha = __builtin_amdgcn_exp2f((m_run - m_new) * LOG2E);
        l_run = l_run * alpha + ps;
        m_run = m_new;
        unsigned short* pwf = pts[wave];
#pragma unroll
        for (int mt = 0; mt < 2; ++mt)
#pragma unroll
            for (int r = 0; r < 4; ++r)
                pwf[c * 40 + mt * 16 + quad * 4 + r] = f2bf(p[mt * 4 + r]);
        float ar[4];
#pragma unroll
        for (int r = 0; r < 4; ++r)
            ar[r] = __shfl(alpha, (quad << 4) + quad * 4 + r, 64);
#pragma unroll
        for (int dc = 0; dc < 4; ++dc)
#pragma unroll
            for (int r = 0; r < 4; ++r) acc[dc][r] *= ar[r];
        bf16x8 pf = __builtin_bit_cast(bf16x8, *(const uint4*)&pwf[c * 40 + quad * 8]);
#pragma unroll
        for (int dc = 0; dc < 4; ++dc) {
            const int vrow = dc * 16 + c;
            const int blk = quad ^ ((vrow >> 3) & 3);
            const unsigned short* vp = &vts[vrow * VT_STRIDE + blk * 8];
            uint2 a0 = *(const uint2*)vp;
            uint2 a1 = *(const uint2*)(vp + 4);
            uint4 u; u.x = a0.x; u.y = a0.y; u.z = a1.x; u.w = a1.y;
            bf16x8 vf = __builtin_bit_cast(bf16x8, u);
            acc[dc] = MFMA16(pf, vf, acc[dc]);
        }
    }
    float linv[4];
#pragma unroll
    for (int r = 0; r < 4; ++r) {
        const float lr = __shfl(l_run, (quad << 4) + quad * 4 + r, 64);
        linv[r] = 1.0f / lr;
    }
    float* ob = out + head_off;
#pragma unroll
    for (int dc = 0; dc < 4; ++dc)
#pragma unroll
        for (int r = 0; r < 4; ++r) {
            const size_t idx = (size_t)(qbase + quad * 4 + r) * DH + dc * 16 + c;
            ob[idx] = acc[dc][r] * linv[r];
        }
}

extern "C" void kernel_launch(void* const* d_in, const int* in_sizes, int n_in,
                              void* d_out, int out_size, void* d_ws, size_t ws_size,
                              hipStream_t stream) {
    const float* q = (const float*)d_in[0];
    const float* k = (const float*)d_in[1];
    const float* v = (const float*)d_in[2];
    float* o = (float*)d_out;
    const size_t need = (size_t)2 * 64 * 64 * 4096;  // K + V bf16 tile images
    if (ws_size >= need) {
        uint4* kimg = (uint4*)d_ws;
        uint4* vimg = kimg + (size_t)64 * 64 * 256;
        hipLaunchKernelGGL(prep_kv, dim3(8192), dim3(256), 0, stream, k, v, kimg, vimg);
        hipLaunchKernelGGL(fa_kernel, dim3(1024), dim3(256), 0, stream, q, kimg, vimg, o);
    } else {
        hipLaunchKernelGGL(fa_kernel_fb, dim3(2048), dim3(256), 0, stream, q, k, v, o);
    }
}

// Round 2
// 188.897 us; speedup vs baseline: 1.2512x; 1.2512x over previous
//
#include <hip/hip_runtime.h>

#define S_LEN 2048
#define DH 64

typedef float f32x4 __attribute__((ext_vector_type(4)));
typedef __bf16 bf16x8 __attribute__((ext_vector_type(8)));
typedef unsigned u32x2v __attribute__((ext_vector_type(2)));

#define MFMA16(A, B, C) __builtin_amdgcn_mfma_f32_16x16x32_bf16(A, B, C, 0, 0, 0)

#ifdef __has_builtin
#if __has_builtin(__builtin_amdgcn_permlane16_swap) && __has_builtin(__builtin_amdgcn_permlane32_swap)
#define HAVE_PLSWAP 1
#endif
#if __has_builtin(__builtin_amdgcn_global_load_lds)
#define HAVE_GLDS 1
#endif
#endif
#ifndef HAVE_PLSWAP
#define HAVE_PLSWAP 0
#endif
#ifndef HAVE_GLDS
#define HAVE_GLDS 0
#endif

__device__ __forceinline__ unsigned short f2bf(float f) {
    unsigned u = __builtin_bit_cast(unsigned, f);
    u += 0x7fffu + ((u >> 16) & 1u);
    return (unsigned short)(u >> 16);
}

__device__ __forceinline__ uint4 pack8(const float* s) {
    unsigned short h[8];
#pragma unroll
    for (int i = 0; i < 8; ++i) h[i] = f2bf(s[i]);
    return *(const uint4*)h;
}

// truncating pack (1 VALU op); bias cancels in O = (P V)/(P 1)
__device__ __forceinline__ unsigned pack_tr(float a, float b) {
    return __builtin_amdgcn_perm(__builtin_bit_cast(unsigned, b),
                                 __builtin_bit_cast(unsigned, a), 0x07060302u);
}

__device__ __forceinline__ bf16x8 ld128(const unsigned short* p) {
    return __builtin_bit_cast(bf16x8, *(const uint4*)p);
}

__device__ __forceinline__ bf16x8 ones8() {
    uint4 ou; ou.x = 0x3F803F80u; ou.y = ou.x; ou.z = ou.x; ou.w = ou.x;
    return __builtin_bit_cast(bf16x8, ou);
}

// ---- cross-lane P redistribution: C-layout (4 keys/lane) -> A-frag --------
// pl32pair: x' = [x.q0,x.q1,y.q0,y.q1], y' = [x.q2,x.q3,y.q2,y.q3]
__device__ __forceinline__ void pl32pair(unsigned& x, unsigned& y) {
#if HAVE_PLSWAP
    u32x2v r = __builtin_amdgcn_permlane32_swap(x, y, false, false);
    x = r[0]; y = r[1];
#else
    unsigned sx = __shfl_xor(x, 32, 64);
    unsigned sy = __shfl_xor(y, 32, 64);
    const bool hi = (threadIdx.x & 32) != 0;
    unsigned nx = hi ? sy : x;
    unsigned ny = hi ? y : sx;
    x = nx; y = ny;
#endif
}

// pl16pair: x' = [x.q0,y.q0,x.q2,y.q2], y' = [x.q1,y.q1,x.q3,y.q3]
__device__ __forceinline__ void pl16pair(unsigned& x, unsigned& y) {
#if HAVE_PLSWAP
    u32x2v r = __builtin_amdgcn_permlane16_swap(x, y, false, false);
    x = r[0]; y = r[1];
#else
    unsigned sx = __shfl_xor(x, 16, 64);
    unsigned sy = __shfl_xor(y, 16, 64);
    const bool odd = (threadIdx.x & 16) != 0;
    unsigned nx = odd ? sy : x;
    unsigned ny = odd ? y : sx;
    x = nx; y = ny;
#endif
}

// Inputs (lane quad q, col c): A0 = keys {4q,4q+1} of mt=2h, B0 = {4q+2,4q+3},
// A1/B1 same for mt=2h+1. Output: A-frag dwords w0..w3, lane q' holding keys
// q'*8..q'*8+7 (relative to the 32-key half) of row c.
__device__ __forceinline__ bf16x8 frag_from(unsigned A0, unsigned B0,
                                            unsigned A1, unsigned B1) {
    pl32pair(A0, A1);   // A0=[a.q0,a.q1,a1.q0,a1.q1]  A1=[a.q2,a.q3,a1.q2,a1.q3]
    pl16pair(A0, A1);   // A0=w0  A1=w2
    pl32pair(B0, B1);
    pl16pair(B0, B1);   // B0=w1  B1=w3
    uint4 u; u.x = A0; u.y = B0; u.z = A1; u.w = B1;
    return __builtin_bit_cast(bf16x8, u);
}

// ---- async global->LDS (16B/lane, linear dest = our exact layout) ---------
__device__ __forceinline__ void glds16(const uint4* g, unsigned short* l) {
#if HAVE_GLDS
    __builtin_amdgcn_global_load_lds(
        (const __attribute__((address_space(1))) uint4*)g,
        (__attribute__((address_space(3))) uint4*)l, 16, 0, 0);
#else
    *(uint4*)l = *g;
#endif
}

// ---------------- fused pre-pass: K and V -> swizzled bf16 tile images -----
__global__ __launch_bounds__(256) void prep_kv(const float* __restrict__ k,
                                               const float* __restrict__ v,
                                               uint4* __restrict__ kimg,
                                               uint4* __restrict__ vimg) {
    __shared__ unsigned short tr[64 * 40];
    const int bid = blockIdx.x;
    const int t = threadIdx.x;
    if (bid < 4096) {
        const int r = t >> 3, b = t & 7;
        const int srcblk = b ^ (r & 7);
        const float* src = k + ((size_t)bid * 32 + r) * 64 + srcblk * 8;
        float buf[8];
        *(float4*)&buf[0] = *(const float4*)src;
        *(float4*)&buf[4] = *(const float4*)(src + 4);
        kimg[(size_t)bid * 256 + t] = pack8(buf);
    } else {
        const int vb = bid - 4096;
        const int r = t >> 3, cb = t & 7;
        const float* src = v + ((size_t)vb * 32 + r) * 64 + cb * 8;
        float buf[8];
        *(float4*)&buf[0] = *(const float4*)src;
        *(float4*)&buf[4] = *(const float4*)(src + 4);
#pragma unroll
        for (int i = 0; i < 8; ++i)
            tr[(cb * 8 + i) * 40 + r] = f2bf(buf[i]);
        __syncthreads();
        const int d = t >> 2, kb = t & 3;
        const int skb = kb ^ ((d >> 1) & 3);
        vimg[(size_t)vb * 256 + t] = *(const uint4*)&tr[d * 40 + skb * 8];
    }
}

// ---------------- main body: two independent 16-row strips -----------------
// MA/MB: apply causal mask to strip A/B. LB: strip B live. SHARED: B uses
// A's tile (phase 1). Non-shared (phase 2): B is a second key-partial of the
// SAME rows as A against a different tile.
template <bool MA, bool MB, bool LB, bool SHARED>
__device__ __forceinline__ void body2(
    const unsigned short* __restrict__ ktA, const unsigned short* __restrict__ vtA,
    const unsigned short* __restrict__ ktB, const unsigned short* __restrict__ vtB,
    const bf16x8* qA, const bf16x8* qB,
    f32x4* accA, f32x4* accB, f32x4& aclA, f32x4& aclB,
    int igA, int igB, int kbA, int kbB, int quad, int c)
{
    const int sw = c & 7;
    const bf16x8 ones = ones8();
    const int f0 = (quad ^ sw) << 3;
    const int f1 = ((quad | 4) ^ sw) << 3;
    bf16x8 pfA[2], pfB[2];
#pragma unroll
    for (int h = 0; h < 2; ++h) {
        unsigned pA[2][2], pB[2][2];
#pragma unroll
        for (int m = 0; m < 2; ++m) {
            const int mt = 2 * h + m;
            const unsigned short* krA = ktA + (mt * 16 + c) * 64;
            bf16x8 kA0 = ld128(krA + f0), kA1 = ld128(krA + f1);
            {
                f32x4 s = (f32x4){0.f, 0.f, 0.f, 0.f};
                s = MFMA16(kA0, qA[0], s);
                s = MFMA16(kA1, qA[1], s);
                float p[4];
#pragma unroll
                for (int r = 0; r < 4; ++r) {
                    float e = __builtin_amdgcn_exp2f(s[r]);
                    if (MA) {
                        const int jg = kbA + mt * 16 + quad * 4 + r;
                        e = (jg > igA) ? 0.f : e;
                    }
                    p[r] = e;
                }
                pA[m][0] = pack_tr(p[0], p[1]);
                pA[m][1] = pack_tr(p[2], p[3]);
            }
            if (LB) {
                bf16x8 kB0, kB1;
                if (SHARED) { kB0 = kA0; kB1 = kA1; }
                else {
                    const unsigned short* krB = ktB + (mt * 16 + c) * 64;
                    kB0 = ld128(krB + f0); kB1 = ld128(krB + f1);
                }
                f32x4 s = (f32x4){0.f, 0.f, 0.f, 0.f};
                s = MFMA16(kB0, qB[0], s);
                s = MFMA16(kB1, qB[1], s);
                float p[4];
#pragma unroll
                for (int r = 0; r < 4; ++r) {
                    float e = __builtin_amdgcn_exp2f(s[r]);
                    if (MB) {
                        const int jg = kbB + mt * 16 + quad * 4 + r;
                        e = (jg > igB) ? 0.f : e;
                    }
                    p[r] = e;
                }
                pB[m][0] = pack_tr(p[0], p[1]);
                pB[m][1] = pack_tr(p[2], p[3]);
            }
        }
        pfA[h] = frag_from(pA[0][0], pA[0][1], pA[1][0], pA[1][1]);
        aclA = MFMA16(pfA[h], ones, aclA);
        if (LB) {
            pfB[h] = frag_from(pB[0][0], pB[0][1], pB[1][0], pB[1][1]);
            aclB = MFMA16(pfB[h], ones, aclB);
        }
    }
    const int vsw = (c >> 1) & 3;
#pragma unroll
    for (int dc = 0; dc < 4; ++dc) {
        const int vo = (dc * 16 + c) * 32 + ((quad ^ vsw) << 3);
        bf16x8 v0 = ld128(vtA + vo), v1 = ld128(vtA + vo + 2048);
        accA[dc] = MFMA16(pfA[0], v0, accA[dc]);
        accA[dc] = MFMA16(pfA[1], v1, accA[dc]);
        if (LB) {
            bf16x8 w0, w1;
            if (SHARED) { w0 = v0; w1 = v1; }
            else { w0 = ld128(vtB + vo); w1 = ld128(vtB + vo + 2048); }
            accB[dc] = MFMA16(pfB[0], w0, accB[dc]);
            accB[dc] = MFMA16(pfB[1], w1, accB[dc]);
        }
    }
}

__device__ __forceinline__ void write_strip(float* __restrict__ ob,
                                            const f32x4* acc, const f32x4 acl,
                                            int rowbase, int quad, int c) {
    float linv[4];
#pragma unroll
    for (int r = 0; r < 4; ++r) linv[r] = 1.0f / acl[r];
#pragma unroll
    for (int dc = 0; dc < 4; ++dc)
#pragma unroll
        for (int r = 0; r < 4; ++r) {
            const size_t idx =
                (size_t)(rowbase + quad * 4 + r) * DH + dc * 16 + c;
            ob[idx] = acc[dc][r] * linv[r];
        }
}

// ---------------- main kernel: pair-chunk key-split, uniform 17 iters ------
// Block ci (0..15) owns 64-row chunk ci (lo) + chunk 31-ci (hi). Each wave
// owns a 16-row strip of each. Phase 1 (jt=0..ci): both strips vs the same
// tile (frags shared). Lo strip hits its diagonal at jt==ci and retires.
// Phase 2 (tiles ci+1..31-ci, two per iteration): s0/s1 are two additive
// key-partials of the SAME hi strip; merged in-register at the end. Every
// block runs exactly 17 full-density iterations -> no tail imbalance.
__global__ __launch_bounds__(256, 4) void fa_kernel(
    const float* __restrict__ q,
    const uint4* __restrict__ kimg,
    const uint4* __restrict__ vimg,
    float* __restrict__ out)
{
    __shared__ unsigned short kt[2][64 * 64];     // 2 x 8 KB
    __shared__ unsigned short vt[2][2 * 64 * 32]; // 2 x 8 KB

    const int tid  = threadIdx.x;
    const int lane = tid & 63;
    const int wave = tid >> 6;
    const int quad = lane >> 4;
    const int c    = lane & 15;

    const int bid = blockIdx.x;
    const int bh  = bid & 63;
    const int ci  = bid >> 6;                     // 0..15
    const int hib = (31 - ci) * 64 + wave * 16;   // hi strip base row
    const int lob = ci * 64 + wave * 16;          // lo strip base row

    const size_t head_off = (size_t)bh * S_LEN * DH;

    const uint4* kin = kimg + (size_t)bh * 16384;
    const uint4* vin = vimg + (size_t)bh * 16384;

    auto stage = [&](int jt, int b) {
        const uint4* kg = kin + jt * 512 + tid;
        const uint4* vg = vin + jt * 512 + tid;
        glds16(kg,       &kt[b][0] + (size_t)tid * 8);
        glds16(kg + 256, &kt[b][0] + (size_t)(tid + 256) * 8);
        glds16(vg,       &vt[b][0] + (size_t)tid * 8);
        glds16(vg + 256, &vt[b][0] + (size_t)(tid + 256) * 8);
    };

    stage(0, 0);  // issue first tile before Q prep; drained at first barrier

    // Q fragments: [0,1] = hi strip, [2,3] = lo strip (log2-domain pre-scale)
    const float SCALE = 0.125f * 1.4426950408889634f;
    bf16x8 qf[4];
#pragma unroll
    for (int s = 0; s < 2; ++s) {
        const int base = s ? lob : hib;
        const float* qrow = q + head_off + (size_t)(base + c) * DH;
        float t0[8], t1[8];
#pragma unroll
        for (int i = 0; i < 8; ++i) t0[i] = qrow[quad * 8 + i] * SCALE;
#pragma unroll
        for (int i = 0; i < 8; ++i) t1[i] = qrow[32 + quad * 8 + i] * SCALE;
        qf[s * 2 + 0] = __builtin_bit_cast(bf16x8, pack8(t0));
        qf[s * 2 + 1] = __builtin_bit_cast(bf16x8, pack8(t1));
    }

    f32x4 accA[4], accB[4];
#pragma unroll
    for (int dc = 0; dc < 4; ++dc) {
        accA[dc] = (f32x4){0.f, 0.f, 0.f, 0.f};
        accB[dc] = (f32x4){0.f, 0.f, 0.f, 0.f};
    }
    f32x4 aclA = (f32x4){0.f, 0.f, 0.f, 0.f};
    f32x4 aclB = (f32x4){0.f, 0.f, 0.f, 0.f};

    const int igA = hib + c;
    const int igB = lob + c;

    // ---- phase 1: jt = 0..ci, one tile/iter, frags shared, 1 barrier/iter
    int cur = 0;
    for (int jt = 0; jt <= ci; ++jt) {
        __syncthreads();                      // drains stage of kt/vt[cur]
        if (jt < ci) stage(jt + 1, cur ^ 1);  // overlaps with compute below
        const int kb = jt * 64;
        if (jt < ci)
            body2<false, false, true, true>(kt[cur], vt[cur], kt[cur], vt[cur],
                                            qf, qf + 2, accA, accB, aclA, aclB,
                                            igA, igB, kb, kb, quad, c);
        else
            body2<false, true, true, true>(kt[cur], vt[cur], kt[cur], vt[cur],
                                           qf, qf + 2, accA, accB, aclA, aclB,
                                           igA, igB, kb, kb, quad, c);
        cur ^= 1;
    }

    // ---- retire lo strip; accB becomes the hi strip's second key-partial
    write_strip(out + head_off, accB, aclB, lob, quad, c);
#pragma unroll
    for (int dc = 0; dc < 4; ++dc) accB[dc] = (f32x4){0.f, 0.f, 0.f, 0.f};
    aclB = (f32x4){0.f, 0.f, 0.f, 0.f};

    // ---- phase 2: tiles ci+1..31-ci, two per iter (last is single = diag)
    for (int i = 0; i <= 15 - ci; ++i) {
        const int t0 = ci + 1 + 2 * i;
        const bool single = (t0 == 31 - ci);
        __syncthreads();                      // all waves done with both bufs
        stage(t0, 0);
        if (!single) stage(t0 + 1, 1);
        __syncthreads();                      // drain staging
        if (single)
            body2<true, false, false, true>(kt[0], vt[0], kt[0], vt[0],
                                            qf, qf, accA, accB, aclA, aclB,
                                            igA, igA, t0 * 64, t0 * 64, quad, c);
        else
            body2<false, false, true, false>(kt[0], vt[0], kt[1], vt[1],
                                             qf, qf, accA, accB, aclA, aclB,
                                             igA, igA, t0 * 64, (t0 + 1) * 64,
                                             quad, c);
    }

    // ---- merge key-partials in-register, final epilogue for hi strip
#pragma unroll
    for (int dc = 0; dc < 4; ++dc) accA[dc] += accB[dc];
    aclA += aclB;
    write_strip(out + head_off, accA, aclA, hib, quad, c);
}

// ---------------- fallback (round-2 style, used if ws too small) ----------
#define KT_STRIDE 88
#define VT_STRIDE 36
__global__ __launch_bounds__(256) void fa_kernel_fb(
    const float* __restrict__ q, const float* __restrict__ k,
    const float* __restrict__ v, float* __restrict__ out)
{
    __shared__ unsigned short kts[32 * KT_STRIDE];
    __shared__ unsigned short vts[64 * VT_STRIDE];
    __shared__ unsigned short pts[4][16 * 40];
    const int tid = threadIdx.x, lane = tid & 63, wave = tid >> 6;
    const int quad = lane >> 4, c = lane & 15;
    const int bid = blockIdx.x, bh = bid & 63, qblk = 31 - (bid >> 6);
    const int qtile = qblk * 4 + wave, qbase = qtile * 16;
    const int my_diag = qtile >> 1, jt_last = (qblk * 4 + 3) >> 1;
    const size_t head_off = (size_t)bh * S_LEN * DH;
    const float* qrow = q + head_off + (size_t)(qbase + c) * DH;
    float qtmp[8];
#pragma unroll
    for (int i = 0; i < 8; ++i) qtmp[i] = qrow[quad * 8 + i];
    bf16x8 qf0 = __builtin_bit_cast(bf16x8, pack8(qtmp));
#pragma unroll
    for (int i = 0; i < 8; ++i) qtmp[i] = qrow[32 + quad * 8 + i];
    bf16x8 qf1 = __builtin_bit_cast(bf16x8, pack8(qtmp));
    f32x4 acc[4];
#pragma unroll
    for (int dc = 0; dc < 4; ++dc) acc[dc] = (f32x4){0.f, 0.f, 0.f, 0.f};
    float m_run = -1e30f, l_run = 0.f;
    const int ig = qbase + c;
    const int srow = tid >> 3, sdb = tid & 7;
    const int vcol = (((srow >> 3) ^ (sdb & 3)) << 3) | (srow & 7);
    const float LOG2E = 1.4426950408889634f;
    for (int jt = 0; jt <= jt_last; ++jt) {
        __syncthreads();
        {
            const size_t g = head_off + (size_t)(jt * 32 + srow) * DH + sdb * 8;
            float kbuf[8];
            *(float4*)&kbuf[0] = *(const float4*)(k + g);
            *(float4*)&kbuf[4] = *(const float4*)(k + g + 4);
            *(uint4*)&kts[srow * KT_STRIDE + sdb * 8] = pack8(kbuf);
            float vbuf[8];
            *(float4*)&vbuf[0] = *(const float4*)(v + g);
            *(float4*)&vbuf[4] = *(const float4*)(v + g + 4);
#pragma unroll
            for (int i = 0; i < 8; ++i)
                vts[(sdb * 8 + i) * VT_STRIDE + vcol] = f2bf(vbuf[i]);
        }
        __syncthreads();
        if (jt > my_diag) continue;
        f32x4 st[2];
#pragma unroll
        for (int mt = 0; mt < 2; ++mt) {
            const unsigned short* krow = &kts[(mt * 16 + c) * KT_STRIDE + quad * 8];
            bf16x8 ka0 = __builtin_bit_cast(bf16x8, *(const uint4*)krow);
            bf16x8 ka1 = __builtin_bit_cast(bf16x8, *(const uint4*)(krow + 32));
            f32x4 a = (f32x4){0.f, 0.f, 0.f, 0.f};
            a = MFMA16(ka0, qf0, a);
            a = MFMA16(ka1, qf1, a);
            st[mt] = a;
        }
        float tv[8];
#pragma unroll
        for (int mt = 0; mt < 2; ++mt)
#pragma unroll
            for (int r = 0; r < 4; ++r) {
                const int jg = jt * 32 + mt * 16 + quad * 4 + r;
                const float s = st[mt][r] * 0.125f;
                tv[mt * 4 + r] = (jg > ig) ? -1e30f : s;
            }
        float tm = tv[0];
#pragma unroll
        for (int i = 1; i < 8; ++i) tm = fmaxf(tm, tv[i]);
        tm = fmaxf(tm, __shfl_xor(tm, 16, 64));
        tm = fmaxf(tm, __shfl_xor(tm, 32, 64));
        const float m_new = fmaxf(m_run, tm);
        const float mb = m_new * LOG2E;
        float p[8], ps = 0.f;
#pragma unroll
        for (int i = 0; i < 8; ++i) {
            p[i] = __builtin_amdgcn_exp2f(tv[i] * LOG2E - mb);
            ps += p[i];
        }
        ps += __shfl_xor(ps, 16, 64);
        ps += __shfl_xor(ps, 32, 64);
        const float alpha = __builtin_amdgcn_exp2f((m_run - m_new) * LOG2E);
        l_run = l_run * alpha + ps;
        m_run = m_new;
        unsigned short* pwf = pts[wave];
#pragma unroll
        for (int mt = 0; mt < 2; ++mt)
#pragma unroll
            for (int r = 0; r < 4; ++r)
                pwf[c * 40 + mt * 16 + quad * 4 + r] = f2bf(p[mt * 4 + r]);
        float ar[4];
#pragma unroll
        for (int r = 0; r < 4; ++r)
            ar[r] = __shfl(alpha, (quad << 4) + quad * 4 + r, 64);
#pragma unroll
        for (int dc = 0; dc < 4; ++dc)
#pragma unroll
            for (int r = 0; r < 4; ++r) acc[dc][r] *= ar[r];
        bf16x8 pf = __builtin_bit_cast(bf16x8, *(const uint4*)&pwf[c * 40 + quad * 8]);
#pragma unroll
        for (int dc = 0; dc < 4; ++dc) {
            const int vrow = dc * 16 + c;
            const int blk = quad ^ ((vrow >> 3) & 3);
            const unsigned short* vp = &vts[vrow * VT_STRIDE + blk * 8];
            uint2 a0 = *(const uint2*)vp;
            uint2 a1 = *(const uint2*)(vp + 4);
            uint4 u; u.x = a0.x; u.y = a0.y; u.z = a1.x; u.w = a1.y;
            bf16x8 vf = __builtin_bit_cast(bf16x8, u);
            acc[dc] = MFMA16(pf, vf, acc[dc]);
        }
    }
    float linv[4];
#pragma unroll
    for (int r = 0; r < 4; ++r) {
        const float lr = __shfl(l_run, (quad << 4) + quad * 4 + r, 64);
        linv[r] = 1.0f / lr;
    }
    float* ob = out + head_off;
#pragma unroll
    for (int dc = 0; dc < 4; ++dc)
#pragma unroll
        for (int r = 0; r < 4; ++r) {
            const size_t idx = (size_t)(qbase + quad * 4 + r) * DH + dc * 16 + c;
            ob[idx] = acc[dc][r] * linv[r];
        }
}

extern "C" void kernel_launch(void* const* d_in, const int* in_sizes, int n_in,
                              void* d_out, int out_size, void* d_ws, size_t ws_size,
                              hipStream_t stream) {
    const float* q = (const float*)d_in[0];
    const float* k = (const float*)d_in[1];
    const float* v = (const float*)d_in[2];
    float* o = (float*)d_out;
    const size_t need = (size_t)2 * 64 * 64 * 4096;  // K + V bf16 tile images
    if (ws_size >= need) {
        uint4* kimg = (uint4*)d_ws;
        uint4* vimg = kimg + (size_t)64 * 64 * 256;
        hipLaunchKernelGGL(prep_kv, dim3(8192), dim3(256), 0, stream, k, v, kimg, vimg);
        hipLaunchKernelGGL(fa_kernel, dim3(1024), dim3(256), 0, stream, q, kimg, vimg, o);
    } else {
        hipLaunchKernelGGL(fa_kernel_fb, dim3(2048), dim3(256), 0, stream, q, k, v, o);
    }
}

// Round 3
// 187.121 us; speedup vs baseline: 1.2631x; 1.0095x over previous
//
#include <hip/hip_runtime.h>

#define S_LEN 2048
#define DH 64

typedef float f32x4 __attribute__((ext_vector_type(4)));
typedef __bf16 bf16x8 __attribute__((ext_vector_type(8)));
typedef unsigned u32x2v __attribute__((ext_vector_type(2)));

#define MFMA16(A, B, C) __builtin_amdgcn_mfma_f32_16x16x32_bf16(A, B, C, 0, 0, 0)

#ifdef __has_builtin
#if __has_builtin(__builtin_amdgcn_permlane16_swap) && __has_builtin(__builtin_amdgcn_permlane32_swap)
#define HAVE_PLSWAP 1
#endif
#if __has_builtin(__builtin_amdgcn_global_load_lds)
#define HAVE_GLDS 1
#endif
#if __has_builtin(__builtin_amdgcn_s_setprio)
#define SETPRIO(x) __builtin_amdgcn_s_setprio(x)
#endif
#endif
#ifndef HAVE_PLSWAP
#define HAVE_PLSWAP 0
#endif
#ifndef HAVE_GLDS
#define HAVE_GLDS 0
#endif
#ifndef SETPRIO
#define SETPRIO(x)
#endif

__device__ __forceinline__ unsigned short f2bf(float f) {
    unsigned u = __builtin_bit_cast(unsigned, f);
    u += 0x7fffu + ((u >> 16) & 1u);
    return (unsigned short)(u >> 16);
}

__device__ __forceinline__ uint4 pack8(const float* s) {
    unsigned short h[8];
#pragma unroll
    for (int i = 0; i < 8; ++i) h[i] = f2bf(s[i]);
    return *(const uint4*)h;
}

// truncating pack (1 VALU op); bias cancels in O = (P V)/(P 1)
__device__ __forceinline__ unsigned pack_tr(float a, float b) {
    return __builtin_amdgcn_perm(__builtin_bit_cast(unsigned, b),
                                 __builtin_bit_cast(unsigned, a), 0x07060302u);
}

__device__ __forceinline__ bf16x8 ld128(const unsigned short* p) {
    return __builtin_bit_cast(bf16x8, *(const uint4*)p);
}

__device__ __forceinline__ bf16x8 ones8() {
    uint4 ou; ou.x = 0x3F803F80u; ou.y = ou.x; ou.z = ou.x; ou.w = ou.x;
    return __builtin_bit_cast(bf16x8, ou);
}

// ---- cross-lane P redistribution: C-layout (4 keys/lane) -> A-frag --------
__device__ __forceinline__ void pl32pair(unsigned& x, unsigned& y) {
#if HAVE_PLSWAP
    u32x2v r = __builtin_amdgcn_permlane32_swap(x, y, false, false);
    x = r[0]; y = r[1];
#else
    unsigned sx = __shfl_xor(x, 32, 64);
    unsigned sy = __shfl_xor(y, 32, 64);
    const bool hi = (threadIdx.x & 32) != 0;
    unsigned nx = hi ? sy : x;
    unsigned ny = hi ? y : sx;
    x = nx; y = ny;
#endif
}

__device__ __forceinline__ void pl16pair(unsigned& x, unsigned& y) {
#if HAVE_PLSWAP
    u32x2v r = __builtin_amdgcn_permlane16_swap(x, y, false, false);
    x = r[0]; y = r[1];
#else
    unsigned sx = __shfl_xor(x, 16, 64);
    unsigned sy = __shfl_xor(y, 16, 64);
    const bool odd = (threadIdx.x & 16) != 0;
    unsigned nx = odd ? sy : x;
    unsigned ny = odd ? y : sx;
    x = nx; y = ny;
#endif
}

// Inputs (lane quad q, col c): A0 = keys {4q,4q+1} of mt=2h, B0 = {4q+2,4q+3},
// A1/B1 same for mt=2h+1. Output: A-frag, lane q' holding keys q'*8..q'*8+7
// (relative to the 32-key half) of row c.
__device__ __forceinline__ bf16x8 frag_from(unsigned A0, unsigned B0,
                                            unsigned A1, unsigned B1) {
    pl32pair(A0, A1);
    pl16pair(A0, A1);   // A0=w0  A1=w2
    pl32pair(B0, B1);
    pl16pair(B0, B1);   // B0=w1  B1=w3
    uint4 u; u.x = A0; u.y = B0; u.z = A1; u.w = B1;
    return __builtin_bit_cast(bf16x8, u);
}

// ---- async global->LDS (16B/lane, linear dest = our exact layout) ---------
__device__ __forceinline__ void glds16(const uint4* g, unsigned short* l) {
#if HAVE_GLDS
    __builtin_amdgcn_global_load_lds(
        (const __attribute__((address_space(1))) uint4*)g,
        (__attribute__((address_space(3))) uint4*)l, 16, 0, 0);
#else
    *(uint4*)l = *g;
#endif
}

// ---------------- fused pre-pass: K and V -> swizzled bf16 tile images -----
__global__ __launch_bounds__(256) void prep_kv(const float* __restrict__ k,
                                               const float* __restrict__ v,
                                               uint4* __restrict__ kimg,
                                               uint4* __restrict__ vimg) {
    __shared__ unsigned short tr[64 * 40];
    const int bid = blockIdx.x;
    const int t = threadIdx.x;
    if (bid < 4096) {
        const int r = t >> 3, b = t & 7;
        const int srcblk = b ^ (r & 7);
        const float* src = k + ((size_t)bid * 32 + r) * 64 + srcblk * 8;
        float buf[8];
        *(float4*)&buf[0] = *(const float4*)src;
        *(float4*)&buf[4] = *(const float4*)(src + 4);
        kimg[(size_t)bid * 256 + t] = pack8(buf);
    } else {
        const int vb = bid - 4096;
        const int r = t >> 3, cb = t & 7;
        const float* src = v + ((size_t)vb * 32 + r) * 64 + cb * 8;
        float buf[8];
        *(float4*)&buf[0] = *(const float4*)src;
        *(float4*)&buf[4] = *(const float4*)(src + 4);
#pragma unroll
        for (int i = 0; i < 8; ++i)
            tr[(cb * 8 + i) * 40 + r] = f2bf(buf[i]);
        __syncthreads();
        const int d = t >> 2, kb = t & 3;
        const int skb = kb ^ ((d >> 1) & 3);
        vimg[(size_t)vb * 256 + t] = *(const uint4*)&tr[d * 40 + skb * 8];
    }
}

// ---------------- dual-strip body (phase 1): frags shared ------------------
// Strip A = hi rows (unmasked here), strip B = lo rows (MB: diagonal mask).
template <bool MB>
__device__ __forceinline__ void body2(
    const unsigned short* __restrict__ kt_, const unsigned short* __restrict__ vt_,
    const bf16x8* qA, const bf16x8* qB,
    f32x4 (&accA)[4], f32x4 (&accB)[4], f32x4& aclA, f32x4& aclB,
    int igB, int kb, int quad, int c)
{
    const int sw = c & 7;
    const bf16x8 ones = ones8();
    const int f0 = (quad ^ sw) << 3;
    const int f1 = ((quad | 4) ^ sw) << 3;
    bf16x8 pfA[2], pfB[2];
#pragma unroll
    for (int h = 0; h < 2; ++h) {
        unsigned pA[2][2], pB[2][2];
#pragma unroll
        for (int m = 0; m < 2; ++m) {
            const int mt = 2 * h + m;
            const unsigned short* kr = kt_ + (mt * 16 + c) * 64;
            bf16x8 k0 = ld128(kr + f0), k1 = ld128(kr + f1);
            {
                f32x4 s = (f32x4){0.f, 0.f, 0.f, 0.f};
                s = MFMA16(k0, qA[0], s);
                s = MFMA16(k1, qA[1], s);
                float p[4];
#pragma unroll
                for (int r = 0; r < 4; ++r) p[r] = __builtin_amdgcn_exp2f(s[r]);
                pA[m][0] = pack_tr(p[0], p[1]);
                pA[m][1] = pack_tr(p[2], p[3]);
            }
            {
                f32x4 s = (f32x4){0.f, 0.f, 0.f, 0.f};
                s = MFMA16(k0, qB[0], s);
                s = MFMA16(k1, qB[1], s);
                float p[4];
#pragma unroll
                for (int r = 0; r < 4; ++r) {
                    float e = __builtin_amdgcn_exp2f(s[r]);
                    if (MB) {
                        const int jg = kb + mt * 16 + quad * 4 + r;
                        e = (jg > igB) ? 0.f : e;
                    }
                    p[r] = e;
                }
                pB[m][0] = pack_tr(p[0], p[1]);
                pB[m][1] = pack_tr(p[2], p[3]);
            }
        }
        pfA[h] = frag_from(pA[0][0], pA[0][1], pA[1][0], pA[1][1]);
        aclA = MFMA16(pfA[h], ones, aclA);
        pfB[h] = frag_from(pB[0][0], pB[0][1], pB[1][0], pB[1][1]);
        aclB = MFMA16(pfB[h], ones, aclB);
    }
    const int vsw = (c >> 1) & 3;
#pragma unroll
    for (int dc = 0; dc < 4; ++dc) {
        const int vo = (dc * 16 + c) * 32 + ((quad ^ vsw) << 3);
        bf16x8 v0 = ld128(vt_ + vo), v1 = ld128(vt_ + vo + 2048);
        accA[dc] = MFMA16(pfA[0], v0, accA[dc]);
        accA[dc] = MFMA16(pfA[1], v1, accA[dc]);
        accB[dc] = MFMA16(pfB[0], v0, accB[dc]);
        accB[dc] = MFMA16(pfB[1], v1, accB[dc]);
    }
}

// ---------------- single-strip body (phase 2): one key-partial -------------
template <bool MASK>
__device__ __forceinline__ void body1(
    const unsigned short* __restrict__ kt_, const unsigned short* __restrict__ vt_,
    const bf16x8* qA, f32x4 (&acc)[4], f32x4& acl,
    int ig, int kb, int quad, int c)
{
    const int sw = c & 7;
    const bf16x8 ones = ones8();
    const int f0 = (quad ^ sw) << 3;
    const int f1 = ((quad | 4) ^ sw) << 3;
    bf16x8 pf[2];
#pragma unroll
    for (int h = 0; h < 2; ++h) {
        unsigned pA[2][2];
#pragma unroll
        for (int m = 0; m < 2; ++m) {
            const int mt = 2 * h + m;
            const unsigned short* kr = kt_ + (mt * 16 + c) * 64;
            bf16x8 k0 = ld128(kr + f0), k1 = ld128(kr + f1);
            f32x4 s = (f32x4){0.f, 0.f, 0.f, 0.f};
            s = MFMA16(k0, qA[0], s);
            s = MFMA16(k1, qA[1], s);
            float p[4];
#pragma unroll
            for (int r = 0; r < 4; ++r) {
                float e = __builtin_amdgcn_exp2f(s[r]);
                if (MASK) {
                    const int jg = kb + mt * 16 + quad * 4 + r;
                    e = (jg > ig) ? 0.f : e;
                }
                p[r] = e;
            }
            pA[m][0] = pack_tr(p[0], p[1]);
            pA[m][1] = pack_tr(p[2], p[3]);
        }
        pf[h] = frag_from(pA[0][0], pA[0][1], pA[1][0], pA[1][1]);
        acl = MFMA16(pf[h], ones, acl);
    }
    const int vsw = (c >> 1) & 3;
#pragma unroll
    for (int dc = 0; dc < 4; ++dc) {
        const int vo = (dc * 16 + c) * 32 + ((quad ^ vsw) << 3);
        bf16x8 v0 = ld128(vt_ + vo), v1 = ld128(vt_ + vo + 2048);
        acc[dc] = MFMA16(pf[0], v0, acc[dc]);
        acc[dc] = MFMA16(pf[1], v1, acc[dc]);
    }
}

__device__ __forceinline__ void write_strip(float* __restrict__ ob,
                                            const f32x4* acc, const f32x4 acl,
                                            int rowbase, int quad, int c) {
    float linv[4];
#pragma unroll
    for (int r = 0; r < 4; ++r) linv[r] = 1.0f / acl[r];
#pragma unroll
    for (int dc = 0; dc < 4; ++dc)
#pragma unroll
        for (int r = 0; r < 4; ++r) {
            const size_t idx =
                (size_t)(rowbase + quad * 4 + r) * DH + dc * 16 + c;
            ob[idx] = acc[dc][r] * linv[r];
        }
}

// ---------------- main kernel: unified loop, 1 barrier/tile, prefetch ------
// Block ci (0..15) owns 64-row chunk ci (lo) + chunk 31-ci (hi). Each wave
// owns a 16-row strip of each. jt = 0..ci: both strips vs the staged tile
// (frags shared); lo strip masked+retired at jt==ci. jt = ci+1..31-ci: one
// key-partial of the hi strip per tile, target alternating accA/accB by
// parity (static call sites); merged in-register at the end. Every tile:
// exactly one __syncthreads, and its stage was issued one full body earlier.
__global__ __launch_bounds__(256, 4) void fa_kernel(
    const float* __restrict__ q,
    const uint4* __restrict__ kimg,
    const uint4* __restrict__ vimg,
    float* __restrict__ out)
{
    __shared__ unsigned short kt[2][64 * 64];     // 2 x 8 KB
    __shared__ unsigned short vt[2][2 * 64 * 32]; // 2 x 8 KB

    const int tid  = threadIdx.x;
    const int lane = tid & 63;
    const int wave = tid >> 6;
    const int quad = lane >> 4;
    const int c    = lane & 15;

    const int bid = blockIdx.x;
    const int bh  = bid & 63;
    const int ci  = bid >> 6;                     // 0..15
    const int last = 31 - ci;
    const int hib = last * 64 + wave * 16;        // hi strip base row
    const int lob = ci * 64 + wave * 16;          // lo strip base row

    const size_t head_off = (size_t)bh * S_LEN * DH;

    const uint4* kin = kimg + (size_t)bh * 16384;
    const uint4* vin = vimg + (size_t)bh * 16384;

    auto stage = [&](int jt, int b) {
        const uint4* kg = kin + jt * 512 + tid;
        const uint4* vg = vin + jt * 512 + tid;
        glds16(kg,       &kt[b][0] + (size_t)tid * 8);
        glds16(kg + 256, &kt[b][0] + (size_t)(tid + 256) * 8);
        glds16(vg,       &vt[b][0] + (size_t)tid * 8);
        glds16(vg + 256, &vt[b][0] + (size_t)(tid + 256) * 8);
    };

    stage(0, 0);  // issue first tile before Q prep; drained at first barrier

    // Q fragments: [0,1] = hi strip, [2,3] = lo strip (log2-domain pre-scale)
    const float SCALE = 0.125f * 1.4426950408889634f;
    bf16x8 qf[4];
#pragma unroll
    for (int s = 0; s < 2; ++s) {
        const int base = s ? lob : hib;
        const float* qrow = q + head_off + (size_t)(base + c) * DH;
        float t0[8], t1[8];
#pragma unroll
        for (int i = 0; i < 8; ++i) t0[i] = qrow[quad * 8 + i] * SCALE;
#pragma unroll
        for (int i = 0; i < 8; ++i) t1[i] = qrow[32 + quad * 8 + i] * SCALE;
        qf[s * 2 + 0] = __builtin_bit_cast(bf16x8, pack8(t0));
        qf[s * 2 + 1] = __builtin_bit_cast(bf16x8, pack8(t1));
    }

    f32x4 accA[4], accB[4];
#pragma unroll
    for (int dc = 0; dc < 4; ++dc) {
        accA[dc] = (f32x4){0.f, 0.f, 0.f, 0.f};
        accB[dc] = (f32x4){0.f, 0.f, 0.f, 0.f};
    }
    f32x4 aclA = (f32x4){0.f, 0.f, 0.f, 0.f};
    f32x4 aclB = (f32x4){0.f, 0.f, 0.f, 0.f};

    const int igA = hib + c;
    const int igB = lob + c;

    // ---- phase 1: jt = 0..ci, dual strips, shared frags ----
    int jt = 0;
    for (; jt <= ci; ++jt) {
        __syncthreads();                      // drains stage(jt)
        if (jt < last) stage(jt + 1, (jt + 1) & 1);
        const unsigned short* K = kt[jt & 1];
        const unsigned short* V = vt[jt & 1];
        SETPRIO(1);
        if (jt < ci)
            body2<false>(K, V, qf, qf + 2, accA, accB, aclA, aclB,
                         igB, jt * 64, quad, c);
        else
            body2<true>(K, V, qf, qf + 2, accA, accB, aclA, aclB,
                        igB, jt * 64, quad, c);
        SETPRIO(0);
    }

    // ---- retire lo strip; accB becomes the hi strip's second key-partial
    write_strip(out + head_off, accB, aclB, lob, quad, c);
#pragma unroll
    for (int dc = 0; dc < 4; ++dc) accB[dc] = (f32x4){0.f, 0.f, 0.f, 0.f};
    aclB = (f32x4){0.f, 0.f, 0.f, 0.f};

    // ---- phase 2: jt = ci+1..last, single strip, alternating partials ----
    for (; jt <= last; ++jt) {
        __syncthreads();                      // drains stage(jt)
        if (jt < last) stage(jt + 1, (jt + 1) & 1);
        const unsigned short* K = kt[jt & 1];
        const unsigned short* V = vt[jt & 1];
        const int kb = jt * 64;
        SETPRIO(1);
        if ((jt ^ ci) & 1) {
            if (jt == last) body1<true >(K, V, qf, accB, aclB, igA, kb, quad, c);
            else            body1<false>(K, V, qf, accB, aclB, igA, kb, quad, c);
        } else {
            if (jt == last) body1<true >(K, V, qf, accA, aclA, igA, kb, quad, c);
            else            body1<false>(K, V, qf, accA, aclA, igA, kb, quad, c);
        }
        SETPRIO(0);
    }

    // ---- merge key-partials in-register, final epilogue for hi strip
#pragma unroll
    for (int dc = 0; dc < 4; ++dc) accA[dc] += accB[dc];
    aclA += aclB;
    write_strip(out + head_off, accA, aclA, hib, quad, c);
}

// ---------------- fallback (round-2 style, used if ws too small) ----------
#define KT_STRIDE 88
#define VT_STRIDE 36
__global__ __launch_bounds__(256) void fa_kernel_fb(
    const float* __restrict__ q, const float* __restrict__ k,
    const float* __restrict__ v, float* __restrict__ out)
{
    __shared__ unsigned short kts[32 * KT_STRIDE];
    __shared__ unsigned short vts[64 * VT_STRIDE];
    __shared__ unsigned short pts[4][16 * 40];
    const int tid = threadIdx.x, lane = tid & 63, wave = tid >> 6;
    const int quad = lane >> 4, c = lane & 15;
    const int bid = blockIdx.x, bh = bid & 63, qblk = 31 - (bid >> 6);
    const int qtile = qblk * 4 + wave, qbase = qtile * 16;
    const int my_diag = qtile >> 1, jt_last = (qblk * 4 + 3) >> 1;
    const size_t head_off = (size_t)bh * S_LEN * DH;
    const float* qrow = q + head_off + (size_t)(qbase + c) * DH;
    float qtmp[8];
#pragma unroll
    for (int i = 0; i < 8; ++i) qtmp[i] = qrow[quad * 8 + i];
    bf16x8 qf0 = __builtin_bit_cast(bf16x8, pack8(qtmp));
#pragma unroll
    for (int i = 0; i < 8; ++i) qtmp[i] = qrow[32 + quad * 8 + i];
    bf16x8 qf1 = __builtin_bit_cast(bf16x8, pack8(qtmp));
    f32x4 acc[4];
#pragma unroll
    for (int dc = 0; dc < 4; ++dc) acc[dc] = (f32x4){0.f, 0.f, 0.f, 0.f};
    float m_run = -1e30f, l_run = 0.f;
    const int ig = qbase + c;
    const int srow = tid >> 3, sdb = tid & 7;
    const int vcol = (((srow >> 3) ^ (sdb & 3)) << 3) | (srow & 7);
    const float LOG2E = 1.4426950408889634f;
    for (int jt = 0; jt <= jt_last; ++jt) {
        __syncthreads();
        {
            const size_t g = head_off + (size_t)(jt * 32 + srow) * DH + sdb * 8;
            float kbuf[8];
            *(float4*)&kbuf[0] = *(const float4*)(k + g);
            *(float4*)&kbuf[4] = *(const float4*)(k + g + 4);
            *(uint4*)&kts[srow * KT_STRIDE + sdb * 8] = pack8(kbuf);
            float vbuf[8];
            *(float4*)&vbuf[0] = *(const float4*)(v + g);
            *(float4*)&vbuf[4] = *(const float4*)(v + g + 4);
#pragma unroll
            for (int i = 0; i < 8; ++i)
                vts[(sdb * 8 + i) * VT_STRIDE + vcol] = f2bf(vbuf[i]);
        }
        __syncthreads();
        if (jt > my_diag) continue;
        f32x4 st[2];
#pragma unroll
        for (int mt = 0; mt < 2; ++mt) {
            const unsigned short* krow = &kts[(mt * 16 + c) * KT_STRIDE + quad * 8];
            bf16x8 ka0 = __builtin_bit_cast(bf16x8, *(const uint4*)krow);
            bf16x8 ka1 = __builtin_bit_cast(bf16x8, *(const uint4*)(krow + 32));
            f32x4 a = (f32x4){0.f, 0.f, 0.f, 0.f};
            a = MFMA16(ka0, qf0, a);
            a = MFMA16(ka1, qf1, a);
            st[mt] = a;
        }
        float tv[8];
#pragma unroll
        for (int mt = 0; mt < 2; ++mt)
#pragma unroll
            for (int r = 0; r < 4; ++r) {
                const int jg = jt * 32 + mt * 16 + quad * 4 + r;
                const float s = st[mt][r] * 0.125f;
                tv[mt * 4 + r] = (jg > ig) ? -1e30f : s;
            }
        float tm = tv[0];
#pragma unroll
        for (int i = 1; i < 8; ++i) tm = fmaxf(tm, tv[i]);
        tm = fmaxf(tm, __shfl_xor(tm, 16, 64));
        tm = fmaxf(tm, __shfl_xor(tm, 32, 64));
        const float m_new = fmaxf(m_run, tm);
        const float mb = m_new * LOG2E;
        float p[8], ps = 0.f;
#pragma unroll
        for (int i = 0; i < 8; ++i) {
            p[i] = __builtin_amdgcn_exp2f(tv[i] * LOG2E - mb);
            ps += p[i];
        }
        ps += __shfl_xor(ps, 16, 64);
        ps += __shfl_xor(ps, 32, 64);
        const float alpha = __builtin_amdgcn_exp2f((m_run - m_new) * LOG2E);
        l_run = l_run * alpha + ps;
        m_run = m_new;
        unsigned short* pwf = pts[wave];
#pragma unroll
        for (int mt = 0; mt < 2; ++mt)
#pragma unroll
            for (int r = 0; r < 4; ++r)
                pwf[c * 40 + mt * 16 + quad * 4 + r] = f2bf(p[mt * 4 + r]);
        float ar[4];
#pragma unroll
        for (int r = 0; r < 4; ++r)
            ar[r] = __shfl(alpha, (quad << 4) + quad * 4 + r, 64);
#pragma unroll
        for (int dc = 0; dc < 4; ++dc)
#pragma unroll
            for (int r = 0; r < 4; ++r) acc[dc][r] *= ar[r];
        bf16x8 pf = __builtin_bit_cast(bf16x8, *(const uint4*)&pwf[c * 40 + quad * 8]);
#pragma unroll
        for (int dc = 0; dc < 4; ++dc) {
            const int vrow = dc * 16 + c;
            const int blk = quad ^ ((vrow >> 3) & 3);
            const unsigned short* vp = &vts[vrow * VT_STRIDE + blk * 8];
            uint2 a0 = *(const uint2*)vp;
            uint2 a1 = *(const uint2*)(vp + 4);
            uint4 u; u.x = a0.x; u.y = a0.y; u.z = a1.x; u.w = a1.y;
            bf16x8 vf = __builtin_bit_cast(bf16x8, u);
            acc[dc] = MFMA16(pf, vf, acc[dc]);
        }
    }
    float linv[4];
#pragma unroll
    for (int r = 0; r < 4; ++r) {
        const float lr = __shfl(l_run, (quad << 4) + quad * 4 + r, 64);
        linv[r] = 1.0f / lr;
    }
    float* ob = out + head_off;
#pragma unroll
    for (int dc = 0; dc < 4; ++dc)
#pragma unroll
        for (int r = 0; r < 4; ++r) {
            const size_t idx = (size_t)(qbase + quad * 4 + r) * DH + dc * 16 + c;
            ob[idx] = acc[dc][r] * linv[r];
        }
}

extern "C" void kernel_launch(void* const* d_in, const int* in_sizes, int n_in,
                              void* d_out, int out_size, void* d_ws, size_t ws_size,
                              hipStream_t stream) {
    const float* q = (const float*)d_in[0];
    const float* k = (const float*)d_in[1];
    const float* v = (const float*)d_in[2];
    float* o = (float*)d_out;
    const size_t need = (size_t)2 * 64 * 64 * 4096;  // K + V bf16 tile images
    if (ws_size >= need) {
        uint4* kimg = (uint4*)d_ws;
        uint4* vimg = kimg + (size_t)64 * 64 * 256;
        hipLaunchKernelGGL(prep_kv, dim3(8192), dim3(256), 0, stream, k, v, kimg, vimg);
        hipLaunchKernelGGL(fa_kernel, dim3(1024), dim3(256), 0, stream, q, kimg, vimg, o);
    } else {
        hipLaunchKernelGGL(fa_kernel_fb, dim3(2048), dim3(256), 0, stream, q, k, v, o);
    }
}